// Round 16
// baseline (463.362 us; speedup 1.0000x reference)
//
#include <hip/hip_runtime.h>

// ---------------------------------------------------------------------------
// SABlock round 30: attn occupancy 4 -> 5 blocks/CU (on r29, 335.0us).
//   attn_logits: MfmaUtil 15 + VALU 40 = 55% issue, HBM 7% -> latency-bound.
//   Kernel uses exactly 32KB LDS + 64 VGPR: 5 blocks/CU fits exactly
//   (5*32KB = 160KB, VGPR 64 <= 512/5). launch_bounds (256,4) -> (256,5).
//   Last residency increment (r18's lever). One-line change; math untouched.
// r29's T1 XCD remap kept (neutral, no cost). Everything else identical.
// ---------------------------------------------------------------------------

#define B_  4
#define N_  1025
#define C_  768
#define H_  12
#define D_  64
#define M_TOT (B_ * N_)      // 4100
#define M_PAD 4224           // 33 * 128
#define KEXP 2304            // 3 * 768
#define NPAD 1088            // 17 * 64

#define OFF_EIND 3148800
#define OFF_EIDX 3465216
#define OFF_FIND 3465628
#define OFF_FIDX 3782044
#define OFF_CLS  3782456

// workspace offsets (floats)
#define WS_F64   0
#define WS_XS    196608      // ushort[4224*2304]  x' A-pattern; later ctx'
#define WS_QKVB  5062656     // ushort[2304*2304]
#define WS_OUTB  7716864     // ushort[768*2304]
#define WS_QE    8601600     // ushort[4*12*1088*128]
#define WS_KE    11943936
#define WS_VT    15286272

// double-region layout (indices into double*)
#define DQ0 0
#define DMS 3072
#define DLG 39936
#define DMX 89136
#define DZ  89184
#define DMV 89232            // 4096 doubles; region ends < 98304 (WS_XS)

// splitter work partition
#define SPLIT_A_ITEMS (M_PAD * 192)          // 811008
#define SPLIT_B1_ITEMS (2304 * 192)          // 442368
#define SPLIT_B2_ITEMS (768 * 192)           // 147456
#define SPLIT_TOTAL (SPLIT_A_ITEMS + SPLIT_B1_ITEMS + SPLIT_B2_ITEMS)
#define SPLIT_BLOCKS ((SPLIT_TOTAL + 255) / 256)   // 5472

// GEMM tiling: qkv 128x128, out 64x128 (both measured-good)
#define QKV_BLOCKS 594
#define OUT_MT 66            // 4224/64
#define OUT_NT 6             // 768/128
#define OUT_BLOCKS (OUT_MT * OUT_NT)   // 396

typedef short s16x8 __attribute__((ext_vector_type(8)));
typedef float f32x4 __attribute__((ext_vector_type(4)));

__device__ inline unsigned short f2bf(float f) {
    unsigned u = __float_as_uint(f);
    u += 0x7FFF + ((u >> 16) & 1);          // RNE to bf16
    return (unsigned short)(u >> 16);
}
__device__ inline float bf2f(unsigned short h) {
    return __uint_as_float(((unsigned)h) << 16);
}

// async global->LDS, 16 bytes/lane; LDS dest = wave-uniform base + lane*16
__device__ __forceinline__ void gl2lds16(const unsigned short* g, unsigned short* l) {
    __builtin_amdgcn_global_load_lds(
        (const __attribute__((address_space(1))) unsigned int*)g,
        (__attribute__((address_space(3))) unsigned int*)l,
        16, 0, 0);
}

// bijective XCD chunk remap (m204): each XCD gets a contiguous run of the
// logical ordering; valid for any nwg (handles nwg%8 != 0).
__device__ inline int xcd_chunk(int lid, int nwg) {
    int xcd = lid & 7, idx = lid >> 3;
    int q = nwg >> 3, r = nwg & 7;
    return (xcd < r ? xcd * (q + 1) : r * (q + 1) + (xcd - r) * q) + idx;
}

// grouped swizzle: 8-wide m super-rows, n fastest inside a super-row (33 rows)
__device__ inline void gemm_decode(int lid, int NT, int& m, int& n) {
    int gi = lid / (8 * NT);
    int r  = lid % (8 * NT);
    int base = gi * 8;
    int gsize = (33 - base < 8) ? (33 - base) : 8;
    n = r / gsize;
    m = base + r % gsize;
}

// generalized decode for MT m-rows
__device__ inline void gemm_decode2(int lid, int MT, int NT, int& m, int& n) {
    int gi = lid / (8 * NT);
    int r  = lid % (8 * NT);
    int base = gi * 8;
    int gsize = (MT - base < 8) ? (MT - base) : 8;
    n = r / gsize;
    m = base + r % gsize;
}

// ---------------------------------------------------------------------------
// L1: split_all + cls_q0
// ---------------------------------------------------------------------------
__global__ __launch_bounds__(256) void fused_split_q0_kernel(
    const float* __restrict__ x, const float* __restrict__ w_qkv,
    const float* __restrict__ w_out,
    unsigned short* __restrict__ xs, unsigned short* __restrict__ qkvB,
    unsigned short* __restrict__ outB, double* __restrict__ dws)
{
    if (blockIdx.x >= SPLIT_BLOCKS) {
        // ---- cls_q0 body ----
        const int t = threadIdx.x;
        const int wg = (blockIdx.x - SPLIT_BLOCKS) * 4 + (t >> 6);
        const int lane = t & 63;
        const int b = wg / 768, rem = wg - b * 768;
        const float* x0 = x + (size_t)b * N_ * C_;
        const float* wr = w_qkv + (size_t)rem * C_;
        double s = 0.0;
        #pragma unroll
        for (int i = 0; i < 12; i++) {
            int c = lane + i*64;
            s += (double)x0[c] * (double)wr[c];
        }
        #pragma unroll
        for (int o = 1; o < 64; o <<= 1) s += __shfl_xor(s, o);
        if (lane == 0) dws[DQ0 + wg] = s * 0.125;
        return;
    }
    // ---- split_all body ----
    int idx = blockIdx.x * 256 + threadIdx.x;
    if (idx < SPLIT_A_ITEMS) {
        int m = idx / 192, c4 = (idx - m * 192) * 4;
        ushort4 hi = make_ushort4(0,0,0,0), lo = hi;
        if (m < M_TOT) {
            float4 f = *(const float4*)&x[(size_t)m * C_ + c4];
            hi.x = f2bf(f.x); hi.y = f2bf(f.y); hi.z = f2bf(f.z); hi.w = f2bf(f.w);
            lo.x = f2bf(f.x - bf2f(hi.x)); lo.y = f2bf(f.y - bf2f(hi.y));
            lo.z = f2bf(f.z - bf2f(hi.z)); lo.w = f2bf(f.w - bf2f(hi.w));
        }
        unsigned short* d = xs + (size_t)m * KEXP + c4;
        *(ushort4*)(d)        = hi;
        *(ushort4*)(d + 768)  = hi;
        *(ushort4*)(d + 1536) = lo;
        return;
    }
    idx -= SPLIT_A_ITEMS;
    const float* src;
    unsigned short* dst;
    if (idx < SPLIT_B1_ITEMS) { src = w_qkv; dst = qkvB; }
    else { idx -= SPLIT_B1_ITEMS; if (idx >= SPLIT_B2_ITEMS) return; src = w_out; dst = outB; }
    int m = idx / 192, c4 = (idx - m * 192) * 4;
    float4 f = *(const float4*)&src[(size_t)m * C_ + c4];
    ushort4 hi, lo;
    hi.x = f2bf(f.x); hi.y = f2bf(f.y); hi.z = f2bf(f.z); hi.w = f2bf(f.w);
    lo.x = f2bf(f.x - bf2f(hi.x)); lo.y = f2bf(f.y - bf2f(hi.y));
    lo.z = f2bf(f.z - bf2f(hi.z)); lo.w = f2bf(f.w - bf2f(hi.w));
    unsigned short* d = dst + (size_t)m * KEXP + c4;
    *(ushort4*)(d)        = hi;
    *(ushort4*)(d + 768)  = lo;
    *(ushort4*)(d + 1536) = hi;
}

// ---------------------------------------------------------------------------
// L2: gemm_qkv 128x128 (3-buffer counted-vmcnt + T2 swizzle + T1 XCD) + cls_ms
// ---------------------------------------------------------------------------
__global__ __launch_bounds__(256) void fused_gemm_qkv_ms_kernel(
    const unsigned short* __restrict__ A, const unsigned short* __restrict__ Bm,
    unsigned short* __restrict__ qe, unsigned short* __restrict__ ke,
    unsigned short* __restrict__ vtp,
    const float* __restrict__ w_qkv, double* __restrict__ dws)
{
    __shared__ unsigned short AsF[3*4096];
    __shared__ unsigned short BsF[3*4096];

    if (blockIdx.x >= QKV_BLOCKS) {
        // ---- cls_ms body (LDS aliased onto AsF) ----
        double* q0s = (double*)AsF;
        const int lid = blockIdx.x - QKV_BLOCKS;
        const int cb = lid % 3;
        const int h  = (lid / 3) % 12;
        const int b  = lid / 36;
        const int t = threadIdx.x;
        const int c = cb * 256 + t;
        if (t < 64) q0s[t] = dws[DQ0 + (b*H_ + h)*64 + t];
        __syncthreads();
        const float* wk = w_qkv + (size_t)(C_ + h*64) * C_ + c;
        double s = 0.0;
        #pragma unroll 8
        for (int d = 0; d < 64; d++) s += q0s[d] * (double)wk[(size_t)d * C_];
        dws[DMS + ((size_t)(b*H_ + h))*768 + c] = s;
        return;
    }

    int mi, ni;
    gemm_decode(xcd_chunk(blockIdx.x, QKV_BLOCKS), 18, mi, ni);
    const int n0 = ni * 128;
    const int m0 = mi * 128;
    const int t = threadIdx.x;
    const int lane = t & 63, wv = t >> 6;
    const int wr = wv >> 1, wc = wv & 1;
    const int q4 = lane >> 4, r = lane & 15;
    const int lrr = lane >> 2;                           // row-within-16 group
    const int lcc = ((lane & 3) ^ ((lane >> 3) & 3)) * 8; // pre-swizzled k-chunk
    const int sw  = (q4 ^ ((r >> 1) & 3)) * 8;            // swizzled read offset

    f32x4 acc[4][4];
    #pragma unroll
    for (int i = 0; i < 4; i++)
        #pragma unroll
        for (int j = 0; j < 4; j++)
            #pragma unroll
            for (int e = 0; e < 4; e++) acc[i][j][e] = 0.f;

    const unsigned short* gA = A  + (size_t)(m0 + wv*16 + lrr) * KEXP + lcc;
    const unsigned short* gB = Bm + (size_t)(n0 + wv*16 + lrr) * KEXP + lcc;

    auto STAGE = [&](int kt, int o) {
        const unsigned short* a = gA + kt * 32;
        const unsigned short* b = gB + kt * 32;
        gl2lds16(a,                       AsF + o + wv*512);
        gl2lds16(a + (size_t)64 * KEXP,   AsF + o + 2048 + wv*512);
        gl2lds16(b,                       BsF + o + wv*512);
        gl2lds16(b + (size_t)64 * KEXP,   BsF + o + 2048 + wv*512);
    };

    // prologue: tiles 0,1 in flight (8 loads/wave)
    STAGE(0, 0);
    STAGE(1, 4096);

    int cb = 0;
    for (int it = 0; it < 72; ++it) {
        // counted wait: own tile-it loads (oldest 4) landed; tile it+1 stays
        // in flight ACROSS the barrier (T4). Last iter drains fully.
        if (it + 1 < 72) asm volatile("s_waitcnt vmcnt(4)" ::: "memory");
        else             asm volatile("s_waitcnt vmcnt(0)" ::: "memory");
        __builtin_amdgcn_s_barrier();
        asm volatile("" ::: "memory");          // no LDS reads hoist above
        __builtin_amdgcn_sched_barrier(0);
        if (it + 2 < 72) {
            int nb = (cb >= 1) ? cb - 1 : cb + 2;   // (cb+2)%3, freed at barrier
            STAGE(it + 2, nb * 4096);
        }
        const int cbuf = cb * 4096;
        s16x8 af[4], bfr[4];
        #pragma unroll
        for (int i = 0; i < 4; i++) {
            af[i]  = *(const s16x8*)&AsF[cbuf + (wr*64 + i*16 + r)*32 + sw];
            bfr[i] = *(const s16x8*)&BsF[cbuf + (wc*64 + i*16 + r)*32 + sw];
        }
        #pragma unroll
        for (int i = 0; i < 4; i++)
            #pragma unroll
            for (int j = 0; j < 4; j++)
                acc[i][j] = __builtin_amdgcn_mfma_f32_16x16x32_bf16(af[i], bfr[j], acc[i][j], 0, 0, 0);
        cb = (cb < 2) ? cb + 1 : 0;
    }

    const int sel = n0 / C_;
    const int off = n0 % C_;
    const float scl = (sel == 0) ? 0.125f : 1.0f;
    #pragma unroll
    for (int i = 0; i < 4; i++) {
        #pragma unroll
        for (int rr = 0; rr < 4; rr++) {
            int gm = m0 + wr*64 + i*16 + q4*4 + rr;
            if (gm < M_TOT) {
                int bb = gm / N_, n = gm - bb * N_;
                #pragma unroll
                for (int j = 0; j < 4; j++) {
                    int col = off + wc*64 + j*16 + r;
                    int h = col >> 6, d = col & 63;
                    float val = acc[i][j][rr] * scl;
                    unsigned short hi = f2bf(val);
                    unsigned short lo = f2bf(val - bf2f(hi));
                    size_t bh = (size_t)(bb*H_ + h);
                    if (sel <= 1) {
                        unsigned short* dst = (sel == 0 ? qe : ke) + (bh*NPAD + n)*128;
                        dst[d]      = hi;
                        dst[64 + d] = lo;
                    } else {
                        unsigned short* dst = vtp + bh*128*NPAD;
                        dst[(size_t)d*NPAD + n]        = hi;
                        dst[(size_t)(64 + d)*NPAD + n] = lo;
                    }
                }
            }
        }
    }
}

// ---------------------------------------------------------------------------
// L3: attn (r18 + setprio, 5 blocks/CU) + cls_logits
// ---------------------------------------------------------------------------
__global__ __launch_bounds__(256, 5) void fused_attn_logits_kernel(
    const unsigned short* __restrict__ qe, const unsigned short* __restrict__ ke,
    const unsigned short* __restrict__ vtp, unsigned short* __restrict__ ctxs,
    const float* __restrict__ x, double* __restrict__ dws)
{
    __shared__ unsigned short KP[64*128];     // 16 KB: K tile, then P (overlay)
    __shared__ unsigned short VP[128*64];     // 16 KB, swizzled

    if (blockIdx.x >= 816) {
        // ---- cls_logits body (LDS aliased onto KP) ----
        double* xsd = (double*)KP;            // 768 doubles = 6 KB
        const int lid = blockIdx.x - 816;
        const int j = lid % 1025, b = lid / 1025;
        const int t = threadIdx.x;
        const int w = t >> 6, lane = t & 63;
        const float* xr = x + ((size_t)b * N_ + j) * C_;
        for (int c = t; c < C_; c += 256) xsd[c] = (double)xr[c];
        __syncthreads();
        for (int hh = 0; hh < 3; hh++) {
            int h = w + hh * 4;
            const double* ms = dws + DMS + ((size_t)(b*H_ + h))*768;
            double s = 0.0;
            #pragma unroll
            for (int i = 0; i < 12; i++) {
                int c = lane + i*64;
                s += xsd[c] * ms[c];
            }
            #pragma unroll
            for (int o = 1; o < 64; o <<= 1) s += __shfl_xor(s, o);
            if (lane == 0) dws[DLG + ((size_t)(b*H_ + h))*1025 + j] = s;
        }
        return;
    }

    const int qt = blockIdx.x / 48;
    const int g  = blockIdx.x - qt * 48;
    const int h = g % 12, b = g / 12;
    const int t = threadIdx.x;
    const int w = t >> 6, lane = t & 63;
    const int quad = lane >> 4, r16 = lane & 15;
    const size_t bh = (size_t)(b*H_ + h);

    // Q fragments (kt-invariant)
    s16x8 ah0, ah1, al0, al1;
    {
        const unsigned short* qrow = qe + (bh*NPAD + qt*64 + w*16 + r16) * 128;
        const int q8 = quad * 8;
        ah0 = *(const s16x8*)(qrow + q8);
        ah1 = *(const s16x8*)(qrow + 32 + q8);
        al0 = *(const s16x8*)(qrow + 64 + q8);
        al1 = *(const s16x8*)(qrow + 96 + q8);
    }

    int qu;
    {
        int rlo = qt*64, rhi = min(qt*64 + 63, N_ - 1);
        if (rlo == 0) qu = -2;
        else { int b1 = (rlo-1)>>8, b2 = (rhi-1)>>8; qu = (b1==b2) ? b1 : -2; }
    }

    float m_run[4], l_run[4];
    f32x4 ctx[4];
    #pragma unroll
    for (int i = 0; i < 4; i++) {
        m_run[i] = -1e30f; l_run[i] = 0.f;
        #pragma unroll
        for (int e = 0; e < 4; e++) ctx[i][e] = 0.f;
    }

    const unsigned short* keb = ke  + (bh*NPAD) * 128;
    const unsigned short* vtb = vtp + bh*(size_t)128*NPAD;

    const int kchunk = (t & 15) ^ ((t >> 4) & 15);
    const int vchunk = (t & 7)  ^ ((t >> 3) & 7);
    const unsigned short* kg0 = keb + (size_t)(t >> 4) * 128 + kchunk * 8;
    const unsigned short* vg0 = vtb + (size_t)(t >> 3) * NPAD + vchunk * 8;

    const int s0 = (quad ^ r16) << 3;
    const int sv = (quad ^ (r16 & 7)) << 3;
    unsigned short* Pew = KP + w*16*128;

    for (int kt = 0; kt < 17; kt++) {
        if (qu >= 0 && kt > 0) {
            int clo = kt*64, chi = min(kt*64 + 63, N_ - 1);
            int b1 = (clo-1)>>8, b2 = (chi-1)>>8;
            if (b1 == b2 && b1 == qu) continue;
        }

        __syncthreads();   // barrier1
        {
            const unsigned short* kg = kg0 + (size_t)kt * 64 * 128;
            const unsigned short* vg = vg0 + kt * 64;
            #pragma unroll
            for (int i = 0; i < 4; i++) {
                gl2lds16(kg + i * 2048,              KP + i*2048 + w*512);
                gl2lds16(vg + (size_t)i * 32 * NPAD, VP + i*2048 + w*512);
            }
        }
        __syncthreads();   // barrier2

        // ---- QK^T ----
        f32x4 st[4];
        #pragma unroll
        for (int j = 0; j < 4; j++)
            #pragma unroll
            for (int e = 0; e < 4; e++) st[j][e] = 0.f;
        __builtin_amdgcn_s_setprio(1);
        #pragma unroll
        for (int j = 0; j < 4; j++) {
            const unsigned short* kr = &KP[(j*16 + r16) * 128];
            s16x8 bh0 = *(const s16x8*)&kr[s0];
            s16x8 bh1 = *(const s16x8*)&kr[s0 ^ 32];
            s16x8 bl0 = *(const s16x8*)&kr[s0 ^ 64];
            s16x8 bl1 = *(const s16x8*)&kr[s0 ^ 96];
            st[j] = __builtin_amdgcn_mfma_f32_16x16x32_bf16(ah0, bh0, st[j], 0,0,0);
            st[j] = __builtin_amdgcn_mfma_f32_16x16x32_bf16(ah1, bh1, st[j], 0,0,0);
            st[j] = __builtin_amdgcn_mfma_f32_16x16x32_bf16(ah0, bl0, st[j], 0,0,0);
            st[j] = __builtin_amdgcn_mfma_f32_16x16x32_bf16(ah1, bl1, st[j], 0,0,0);
            st[j] = __builtin_amdgcn_mfma_f32_16x16x32_bf16(al0, bh0, st[j], 0,0,0);
            st[j] = __builtin_amdgcn_mfma_f32_16x16x32_bf16(al1, bh1, st[j], 0,0,0);
        }
        __builtin_amdgcn_s_setprio(0);

        // ---- online softmax ----
        float pv[4][4];
        float alpha[4];
        #pragma unroll
        for (int reg = 0; reg < 4; reg++) {
            int gr = qt*64 + w*16 + quad*4 + reg;
            int qb = (gr >= 1) ? ((gr - 1) >> 8) : -1;
            float mx = -1e30f;
            float vv[4];
            #pragma unroll
            for (int j = 0; j < 4; j++) {
                int gc = kt*64 + j*16 + r16;
                bool ok = (gr < N_) && (gc < N_) &&
                          !((gr >= 1) && (gc >= 1) && (((gc - 1) >> 8) == qb));
                vv[j] = ok ? st[j][reg] : -1e30f;
                mx = fmaxf(mx, vv[j]);
            }
            mx = fmaxf(mx, __shfl_xor(mx, 1));
            mx = fmaxf(mx, __shfl_xor(mx, 2));
            mx = fmaxf(mx, __shfl_xor(mx, 4));
            mx = fmaxf(mx, __shfl_xor(mx, 8));
            float mnew = fmaxf(m_run[reg], mx);
            alpha[reg] = __expf(m_run[reg] - mnew);
            m_run[reg] = mnew;
            float ps = 0.f;
            #pragma unroll
            for (int j = 0; j < 4; j++) {
                float pp = (vv[j] > -1e29f) ? __expf(vv[j] - mnew) : 0.f;
                pv[reg][j] = pp; ps += pp;
            }
            ps += __shfl_xor(ps, 1);
            ps += __shfl_xor(ps, 2);
            ps += __shfl_xor(ps, 4);
            ps += __shfl_xor(ps, 8);
            l_run[reg] = l_run[reg] * alpha[reg] + ps;
        }

        __syncthreads();   // barrier3: K dead -> P overlay OK

        #pragma unroll
        for (int reg = 0; reg < 4; reg++) {
            int lrow = quad*4 + reg;
            #pragma unroll
            for (int j = 0; j < 4; j++) {
                float pp = pv[reg][j];
                unsigned short ph = f2bf(pp);
                unsigned short pl = f2bf(pp - bf2f(ph));
                int colh = j*16 + r16;
                int coll = 64 + colh;
                Pew[lrow*128 + (((colh >> 3) ^ lrow) << 3) + (colh & 7)] = ph;
                Pew[lrow*128 + (((coll >> 3) ^ lrow) << 3) + (coll & 7)] = pl;
            }
        }

        #pragma unroll
        for (int nj = 0; nj < 4; nj++)
            #pragma unroll
            for (int reg = 0; reg < 4; reg++)
                ctx[nj][reg] *= alpha[reg];

        // ---- PV ----
        {
            const unsigned short* pr = &Pew[r16 * 128];
            s16x8 ph0 = *(const s16x8*)&pr[s0];
            s16x8 ph1 = *(const s16x8*)&pr[s0 ^ 32];
            s16x8 pl0 = *(const s16x8*)&pr[s0 ^ 64];
            s16x8 pl1 = *(const s16x8*)&pr[s0 ^ 96];
            __builtin_amdgcn_s_setprio(1);
            #pragma unroll
            for (int nj = 0; nj < 4; nj++) {
                const unsigned short* vh = &VP[(nj*16 + r16) * 64];
                const unsigned short* vl = &VP[(64 + nj*16 + r16) * 64];
                s16x8 vh0 = *(const s16x8*)&vh[sv];
                s16x8 vh1 = *(const s16x8*)&vh[sv ^ 32];
                s16x8 vl0 = *(const s16x8*)&vl[sv];
                s16x8 vl1 = *(const s16x8*)&vl[sv ^ 32];
                ctx[nj] = __builtin_amdgcn_mfma_f32_16x16x32_bf16(ph0, vh0, ctx[nj], 0,0,0);
                ctx[nj] = __builtin_amdgcn_mfma_f32_16x16x32_bf16(ph1, vh1, ctx[nj], 0,0,0);
                ctx[nj] = __builtin_amdgcn_mfma_f32_16x16x32_bf16(ph0, vl0, ctx[nj], 0,0,0);
                ctx[nj] = __builtin_amdgcn_mfma_f32_16x16x32_bf16(ph1, vl1, ctx[nj], 0,0,0);
                ctx[nj] = __builtin_amdgcn_mfma_f32_16x16x32_bf16(pl0, vh0, ctx[nj], 0,0,0);
                ctx[nj] = __builtin_amdgcn_mfma_f32_16x16x32_bf16(pl1, vh1, ctx[nj], 0,0,0);
            }
            __builtin_amdgcn_s_setprio(0);
        }
    }

    #pragma unroll
    for (int reg = 0; reg < 4; reg++) {
        int gr = qt*64 + w*16 + quad*4 + reg;
        if (gr < N_) {
            float inv = 1.0f / l_run[reg];
            size_t row = (size_t)(b*N_ + gr) * KEXP;
            #pragma unroll
            for (int nj = 0; nj < 4; nj++) {
                float val = ctx[nj][reg] * inv;
                unsigned short hi = f2bf(val);
                unsigned short lo = f2bf(val - bf2f(hi));
                int c = h*64 + nj*16 + r16;
                ctxs[row + c]        = hi;
                ctxs[row + 768 + c]  = hi;
                ctxs[row + 1536 + c] = lo;
            }
        }
    }
}

// ---------------------------------------------------------------------------
// L4: gemm_out 64x128 (+ T1 XCD) + cls_reduce
// ---------------------------------------------------------------------------
__global__ __launch_bounds__(256, 4) void fused_gemm_out_reduce_kernel(
    const unsigned short* __restrict__ A, const unsigned short* __restrict__ Bm,
    const float* __restrict__ bias, float* __restrict__ out,
    double* __restrict__ dws)
{
    __shared__ unsigned short AsF[3*2048];
    __shared__ unsigned short BsF[3*4096];

    if (blockIdx.x >= OUT_BLOCKS) {
        // ---- cls_reduce body (LDS aliased onto AsF) ----
        double* red = (double*)AsF;           // 256 doubles = 2 KB
        const int lid = blockIdx.x - OUT_BLOCKS;
        const int h = lid % 12, b = lid / 12;
        const int t = threadIdx.x;
        const double* lg = dws + DLG + ((size_t)(b*H_ + h))*1025;
        double mloc = -1e300;
        for (int j = t; j < N_; j += 256) mloc = fmax(mloc, lg[j]);
        red[t] = mloc; __syncthreads();
        for (int o = 128; o > 0; o >>= 1) {
            if (t < o) red[t] = fmax(red[t], red[t+o]);
            __syncthreads();
        }
        double mx = red[0]; __syncthreads();
        double sloc = 0.0;
        for (int j = t; j < N_; j += 256) sloc += exp(lg[j] - mx);
        red[t] = sloc; __syncthreads();
        for (int o = 128; o > 0; o >>= 1) {
            if (t < o) red[t] += red[t+o];
            __syncthreads();
        }
        if (t == 0) {
            dws[DMX + b*H_ + h] = mx;
            dws[DZ  + b*H_ + h] = red[0];
        }
        return;
    }

    int mi, ni;
    gemm_decode2(xcd_chunk(blockIdx.x, OUT_BLOCKS), OUT_MT, OUT_NT, mi, ni);
    const int n0 = ni * 128;
    const int m0 = mi * 64;
    const int t = threadIdx.x;
    const int lane = t & 63, wv = t >> 6;
    const int q4 = lane >> 4, r = lane & 15;
    const int lrr = lane >> 2;
    const int lcc = ((lane & 3) ^ ((lane >> 3) & 3)) * 8;
    const int sw  = (q4 ^ ((r >> 1) & 3)) * 8;

    f32x4 acc[4][2];
    #pragma unroll
    for (int i = 0; i < 4; i++)
        #pragma unroll
        for (int j = 0; j < 2; j++)
            #pragma unroll
            for (int e = 0; e < 4; e++) acc[i][j][e] = 0.f;

    const unsigned short* gA = A  + (size_t)(m0 + wv*16 + lrr) * KEXP + lcc;
    const unsigned short* gB = Bm + (size_t)(n0 + wv*16 + lrr) * KEXP + lcc;

    auto STAGE = [&](int kt, int buf) {
        const unsigned short* a = gA + kt * 32;
        const unsigned short* b = gB + kt * 32;
        gl2lds16(a,                       AsF + buf*2048 + wv*512);
        gl2lds16(b,                       BsF + buf*4096 + wv*512);
        gl2lds16(b + (size_t)64 * KEXP,   BsF + buf*4096 + 2048 + wv*512);
    };

    STAGE(0, 0);
    STAGE(1, 1);

    int cb = 0;
    for (int it = 0; it < 72; ++it) {
        if (it + 1 < 72) asm volatile("s_waitcnt vmcnt(3)" ::: "memory");
        else             asm volatile("s_waitcnt vmcnt(0)" ::: "memory");
        __builtin_amdgcn_s_barrier();
        asm volatile("" ::: "memory");
        __builtin_amdgcn_sched_barrier(0);
        if (it + 2 < 72) {
            int nb = (cb >= 1) ? cb - 1 : cb + 2;
            STAGE(it + 2, nb);
        }
        const int cA = cb * 2048, cB = cb * 4096;
        s16x8 af[4], bfr[2];
        #pragma unroll
        for (int i = 0; i < 4; i++)
            af[i]  = *(const s16x8*)&AsF[cA + (i*16 + r)*32 + sw];
        #pragma unroll
        for (int j = 0; j < 2; j++)
            bfr[j] = *(const s16x8*)&BsF[cB + (wv*32 + j*16 + r)*32 + sw];
        #pragma unroll
        for (int i = 0; i < 4; i++)
            #pragma unroll
            for (int j = 0; j < 2; j++)
                acc[i][j] = __builtin_amdgcn_mfma_f32_16x16x32_bf16(af[i], bfr[j], acc[i][j], 0, 0, 0);
        cb = (cb < 2) ? cb + 1 : 0;
    }

    #pragma unroll
    for (int i = 0; i < 4; i++) {
        #pragma unroll
        for (int rr = 0; rr < 4; rr++) {
            int gm = m0 + i*16 + q4*4 + rr;
            if (gm < M_TOT) {
                #pragma unroll
                for (int j = 0; j < 2; j++) {
                    int col = n0 + wv*32 + j*16 + r;
                    out[(size_t)gm * C_ + col] = acc[i][j][rr] + bias[col];
                }
            }
        }
    }
}

// ---------------------------------------------------------------------------
// cls tail: score, rank, fill (r21/r25 measured-good 3-kernel version)
// ---------------------------------------------------------------------------
__global__ __launch_bounds__(256) void cls_score_kernel(
    const double* __restrict__ dwsr, double* __restrict__ dws,
    float* __restrict__ out)
{
    const int idx = blockIdx.x * 256 + threadIdx.x;   // 0..4095
    const int b = idx >> 10, t = idx & 1023;
    double s = 0.0;
    #pragma unroll
    for (int h = 0; h < H_; h++) {
        double mx = dwsr[DMX + b*H_ + h];
        double Z  = dwsr[DZ  + b*H_ + h];
        double lg = dwsr[DLG + ((size_t)(b*H_ + h))*1025 + (t + 1)];
        s += exp(lg - mx) / Z;
    }
    s *= (1.0 / 12.0);
    dws[DMV + idx] = s;
    out[OFF_CLS + (size_t)b*1024 + t] = (float)s;
}

__global__ __launch_bounds__(256) void cls_rank_kernel(
    const double* __restrict__ dws, float* __restrict__ out)
{
    __shared__ double mv[1024];
    const int q = blockIdx.x, b = blockIdx.y;
    const int tid = threadIdx.x;
    for (int i = tid; i < 1024; i += 256) mv[i] = dws[DMV + b*1024 + i];
    __syncthreads();
    const int t = q*256 + tid;
    const double v = mv[t];
    int cd = 0, ca = 0;
    #pragma unroll 8
    for (int j = 0; j < 1024; j++) {
        double u = mv[j];
        bool tie = (u == v) && (j < t);
        cd += (u > v) || tie;
        ca += (u < v) || tie;
    }
    if (cd < 103) out[OFF_EIDX + (size_t)b*103 + cd] = (float)t;
    if (ca < 103) out[OFF_FIDX + (size_t)b*103 + ca] = (float)t;
}

__global__ __launch_bounds__(256) void cls_fill_kernel(float* __restrict__ out)
{
    const int PER = 103 * 192;                   // float4 per (array,b)
    int idx = blockIdx.x * 256 + threadIdx.x;
    if (idx >= 2 * 4 * PER) return;
    int sel = idx / (4 * PER);                   // 0 = enhance, 1 = fuse
    int r   = idx - sel * 4 * PER;
    int b   = r / PER;
    int rem = r - b * PER;
    int e   = rem / 192;
    int c4  = (rem - e * 192) * 4;
    float val = out[(sel ? OFF_FIDX : OFF_EIDX) + (size_t)b*103 + e];
    float* dst = out + (sel ? OFF_FIND : OFF_EIND) + ((size_t)b*103 + e)*768 + c4;
    *(float4*)dst = make_float4(val, val, val, val);
}

// ---------------------------------------------------------------------------
extern "C" void kernel_launch(void* const* d_in, const int* in_sizes, int n_in,
                              void* d_out, int out_size, void* d_ws, size_t ws_size,
                              hipStream_t stream)
{
    const float* x     = (const float*)d_in[0];
    const float* w_qkv = (const float*)d_in[1];
    const float* w_out = (const float*)d_in[2];
    const float* b_out = (const float*)d_in[3];
    float* out = (float*)d_out;
    float* ws  = (float*)d_ws;

    double* dws = (double*)(ws + WS_F64);
    unsigned short* xs   = (unsigned short*)(ws + WS_XS);   // x'; later ctx'
    unsigned short* qkvB = (unsigned short*)(ws + WS_QKVB);
    unsigned short* outB = (unsigned short*)(ws + WS_OUTB);
    unsigned short* qe   = (unsigned short*)(ws + WS_QE);
    unsigned short* ke   = (unsigned short*)(ws + WS_KE);
    unsigned short* vtp  = (unsigned short*)(ws + WS_VT);

    fused_split_q0_kernel<<<SPLIT_BLOCKS + 768, 256, 0, stream>>>(
        x, w_qkv, w_out, xs, qkvB, outB, dws);

    fused_gemm_qkv_ms_kernel<<<QKV_BLOCKS + 144, 256, 0, stream>>>(
        xs, qkvB, qe, ke, vtp, w_qkv, dws);

    fused_attn_logits_kernel<<<816 + 4100, 256, 0, stream>>>(
        qe, ke, vtp, xs, x, dws);

    fused_gemm_out_reduce_kernel<<<OUT_BLOCKS + 48, 256, 0, stream>>>(
        xs, outB, b_out, out, dws);

    cls_score_kernel<<<16, 256, 0, stream>>>(dws, dws, out);
    cls_rank_kernel<<<dim3(4, B_), 256, 0, stream>>>(dws, out);
    cls_fill_kernel<<<618, 256, 0, stream>>>(out);
}

// Round 17
// 334.057 us; speedup vs baseline: 1.3871x; 1.3871x over previous
//
#include <hip/hip_runtime.h>

// ---------------------------------------------------------------------------
// SABlock round 31 = r29 verbatim (measured 335.0us best).
//   r30 post-mortem: launch_bounds (256,5) forced VGPR 64->48, spilling the
//   attn working set (Q frags + ctx + softmax state) to scratch: FETCH
//   30MB->209MB, attn 101->225us. Occupancy-vs-register cliff. Reverted.
//   Config: fat-fused pipeline (split+q0 / gemm_qkv+ms / attn+logits /
//   gemm_out+reduce / score/rank/fill), gemm_qkv 128x128 + counted vmcnt(4)
//   + T2 swizzle + T1 XCD remap, gemm_out 64x128 + vmcnt(3) + T1,
//   attn 32KB LDS + (256,4) + setprio.
// ---------------------------------------------------------------------------

#define B_  4
#define N_  1025
#define C_  768
#define H_  12
#define D_  64
#define M_TOT (B_ * N_)      // 4100
#define M_PAD 4224           // 33 * 128
#define KEXP 2304            // 3 * 768
#define NPAD 1088            // 17 * 64

#define OFF_EIND 3148800
#define OFF_EIDX 3465216
#define OFF_FIND 3465628
#define OFF_FIDX 3782044
#define OFF_CLS  3782456

// workspace offsets (floats)
#define WS_F64   0
#define WS_XS    196608      // ushort[4224*2304]  x' A-pattern; later ctx'
#define WS_QKVB  5062656     // ushort[2304*2304]
#define WS_OUTB  7716864     // ushort[768*2304]
#define WS_QE    8601600     // ushort[4*12*1088*128]
#define WS_KE    11943936
#define WS_VT    15286272

// double-region layout (indices into double*)
#define DQ0 0
#define DMS 3072
#define DLG 39936
#define DMX 89136
#define DZ  89184
#define DMV 89232            // 4096 doubles; region ends < 98304 (WS_XS)

// splitter work partition
#define SPLIT_A_ITEMS (M_PAD * 192)          // 811008
#define SPLIT_B1_ITEMS (2304 * 192)          // 442368
#define SPLIT_B2_ITEMS (768 * 192)           // 147456
#define SPLIT_TOTAL (SPLIT_A_ITEMS + SPLIT_B1_ITEMS + SPLIT_B2_ITEMS)
#define SPLIT_BLOCKS ((SPLIT_TOTAL + 255) / 256)   // 5472

// GEMM tiling: qkv 128x128, out 64x128 (both measured-good)
#define QKV_BLOCKS 594
#define OUT_MT 66            // 4224/64
#define OUT_NT 6             // 768/128
#define OUT_BLOCKS (OUT_MT * OUT_NT)   // 396

typedef short s16x8 __attribute__((ext_vector_type(8)));
typedef float f32x4 __attribute__((ext_vector_type(4)));

__device__ inline unsigned short f2bf(float f) {
    unsigned u = __float_as_uint(f);
    u += 0x7FFF + ((u >> 16) & 1);          // RNE to bf16
    return (unsigned short)(u >> 16);
}
__device__ inline float bf2f(unsigned short h) {
    return __uint_as_float(((unsigned)h) << 16);
}

// async global->LDS, 16 bytes/lane; LDS dest = wave-uniform base + lane*16
__device__ __forceinline__ void gl2lds16(const unsigned short* g, unsigned short* l) {
    __builtin_amdgcn_global_load_lds(
        (const __attribute__((address_space(1))) unsigned int*)g,
        (__attribute__((address_space(3))) unsigned int*)l,
        16, 0, 0);
}

// bijective XCD chunk remap (m204): each XCD gets a contiguous run of the
// logical ordering; valid for any nwg (handles nwg%8 != 0).
__device__ inline int xcd_chunk(int lid, int nwg) {
    int xcd = lid & 7, idx = lid >> 3;
    int q = nwg >> 3, r = nwg & 7;
    return (xcd < r ? xcd * (q + 1) : r * (q + 1) + (xcd - r) * q) + idx;
}

// grouped swizzle: 8-wide m super-rows, n fastest inside a super-row (33 rows)
__device__ inline void gemm_decode(int lid, int NT, int& m, int& n) {
    int gi = lid / (8 * NT);
    int r  = lid % (8 * NT);
    int base = gi * 8;
    int gsize = (33 - base < 8) ? (33 - base) : 8;
    n = r / gsize;
    m = base + r % gsize;
}

// generalized decode for MT m-rows
__device__ inline void gemm_decode2(int lid, int MT, int NT, int& m, int& n) {
    int gi = lid / (8 * NT);
    int r  = lid % (8 * NT);
    int base = gi * 8;
    int gsize = (MT - base < 8) ? (MT - base) : 8;
    n = r / gsize;
    m = base + r % gsize;
}

// ---------------------------------------------------------------------------
// L1: split_all + cls_q0
// ---------------------------------------------------------------------------
__global__ __launch_bounds__(256) void fused_split_q0_kernel(
    const float* __restrict__ x, const float* __restrict__ w_qkv,
    const float* __restrict__ w_out,
    unsigned short* __restrict__ xs, unsigned short* __restrict__ qkvB,
    unsigned short* __restrict__ outB, double* __restrict__ dws)
{
    if (blockIdx.x >= SPLIT_BLOCKS) {
        // ---- cls_q0 body ----
        const int t = threadIdx.x;
        const int wg = (blockIdx.x - SPLIT_BLOCKS) * 4 + (t >> 6);
        const int lane = t & 63;
        const int b = wg / 768, rem = wg - b * 768;
        const float* x0 = x + (size_t)b * N_ * C_;
        const float* wr = w_qkv + (size_t)rem * C_;
        double s = 0.0;
        #pragma unroll
        for (int i = 0; i < 12; i++) {
            int c = lane + i*64;
            s += (double)x0[c] * (double)wr[c];
        }
        #pragma unroll
        for (int o = 1; o < 64; o <<= 1) s += __shfl_xor(s, o);
        if (lane == 0) dws[DQ0 + wg] = s * 0.125;
        return;
    }
    // ---- split_all body ----
    int idx = blockIdx.x * 256 + threadIdx.x;
    if (idx < SPLIT_A_ITEMS) {
        int m = idx / 192, c4 = (idx - m * 192) * 4;
        ushort4 hi = make_ushort4(0,0,0,0), lo = hi;
        if (m < M_TOT) {
            float4 f = *(const float4*)&x[(size_t)m * C_ + c4];
            hi.x = f2bf(f.x); hi.y = f2bf(f.y); hi.z = f2bf(f.z); hi.w = f2bf(f.w);
            lo.x = f2bf(f.x - bf2f(hi.x)); lo.y = f2bf(f.y - bf2f(hi.y));
            lo.z = f2bf(f.z - bf2f(hi.z)); lo.w = f2bf(f.w - bf2f(hi.w));
        }
        unsigned short* d = xs + (size_t)m * KEXP + c4;
        *(ushort4*)(d)        = hi;
        *(ushort4*)(d + 768)  = hi;
        *(ushort4*)(d + 1536) = lo;
        return;
    }
    idx -= SPLIT_A_ITEMS;
    const float* src;
    unsigned short* dst;
    if (idx < SPLIT_B1_ITEMS) { src = w_qkv; dst = qkvB; }
    else { idx -= SPLIT_B1_ITEMS; if (idx >= SPLIT_B2_ITEMS) return; src = w_out; dst = outB; }
    int m = idx / 192, c4 = (idx - m * 192) * 4;
    float4 f = *(const float4*)&src[(size_t)m * C_ + c4];
    ushort4 hi, lo;
    hi.x = f2bf(f.x); hi.y = f2bf(f.y); hi.z = f2bf(f.z); hi.w = f2bf(f.w);
    lo.x = f2bf(f.x - bf2f(hi.x)); lo.y = f2bf(f.y - bf2f(hi.y));
    lo.z = f2bf(f.z - bf2f(hi.z)); lo.w = f2bf(f.w - bf2f(hi.w));
    unsigned short* d = dst + (size_t)m * KEXP + c4;
    *(ushort4*)(d)        = hi;
    *(ushort4*)(d + 768)  = lo;
    *(ushort4*)(d + 1536) = hi;
}

// ---------------------------------------------------------------------------
// L2: gemm_qkv 128x128 (3-buffer counted-vmcnt + T2 swizzle + T1 XCD) + cls_ms
// ---------------------------------------------------------------------------
__global__ __launch_bounds__(256) void fused_gemm_qkv_ms_kernel(
    const unsigned short* __restrict__ A, const unsigned short* __restrict__ Bm,
    unsigned short* __restrict__ qe, unsigned short* __restrict__ ke,
    unsigned short* __restrict__ vtp,
    const float* __restrict__ w_qkv, double* __restrict__ dws)
{
    __shared__ unsigned short AsF[3*4096];
    __shared__ unsigned short BsF[3*4096];

    if (blockIdx.x >= QKV_BLOCKS) {
        // ---- cls_ms body (LDS aliased onto AsF) ----
        double* q0s = (double*)AsF;
        const int lid = blockIdx.x - QKV_BLOCKS;
        const int cb = lid % 3;
        const int h  = (lid / 3) % 12;
        const int b  = lid / 36;
        const int t = threadIdx.x;
        const int c = cb * 256 + t;
        if (t < 64) q0s[t] = dws[DQ0 + (b*H_ + h)*64 + t];
        __syncthreads();
        const float* wk = w_qkv + (size_t)(C_ + h*64) * C_ + c;
        double s = 0.0;
        #pragma unroll 8
        for (int d = 0; d < 64; d++) s += q0s[d] * (double)wk[(size_t)d * C_];
        dws[DMS + ((size_t)(b*H_ + h))*768 + c] = s;
        return;
    }

    int mi, ni;
    gemm_decode(xcd_chunk(blockIdx.x, QKV_BLOCKS), 18, mi, ni);
    const int n0 = ni * 128;
    const int m0 = mi * 128;
    const int t = threadIdx.x;
    const int lane = t & 63, wv = t >> 6;
    const int wr = wv >> 1, wc = wv & 1;
    const int q4 = lane >> 4, r = lane & 15;
    const int lrr = lane >> 2;                           // row-within-16 group
    const int lcc = ((lane & 3) ^ ((lane >> 3) & 3)) * 8; // pre-swizzled k-chunk
    const int sw  = (q4 ^ ((r >> 1) & 3)) * 8;            // swizzled read offset

    f32x4 acc[4][4];
    #pragma unroll
    for (int i = 0; i < 4; i++)
        #pragma unroll
        for (int j = 0; j < 4; j++)
            #pragma unroll
            for (int e = 0; e < 4; e++) acc[i][j][e] = 0.f;

    const unsigned short* gA = A  + (size_t)(m0 + wv*16 + lrr) * KEXP + lcc;
    const unsigned short* gB = Bm + (size_t)(n0 + wv*16 + lrr) * KEXP + lcc;

    auto STAGE = [&](int kt, int o) {
        const unsigned short* a = gA + kt * 32;
        const unsigned short* b = gB + kt * 32;
        gl2lds16(a,                       AsF + o + wv*512);
        gl2lds16(a + (size_t)64 * KEXP,   AsF + o + 2048 + wv*512);
        gl2lds16(b,                       BsF + o + wv*512);
        gl2lds16(b + (size_t)64 * KEXP,   BsF + o + 2048 + wv*512);
    };

    // prologue: tiles 0,1 in flight (8 loads/wave)
    STAGE(0, 0);
    STAGE(1, 4096);

    int cb = 0;
    for (int it = 0; it < 72; ++it) {
        // counted wait: own tile-it loads (oldest 4) landed; tile it+1 stays
        // in flight ACROSS the barrier (T4). Last iter drains fully.
        if (it + 1 < 72) asm volatile("s_waitcnt vmcnt(4)" ::: "memory");
        else             asm volatile("s_waitcnt vmcnt(0)" ::: "memory");
        __builtin_amdgcn_s_barrier();
        asm volatile("" ::: "memory");          // no LDS reads hoist above
        __builtin_amdgcn_sched_barrier(0);
        if (it + 2 < 72) {
            int nb = (cb >= 1) ? cb - 1 : cb + 2;   // (cb+2)%3, freed at barrier
            STAGE(it + 2, nb * 4096);
        }
        const int cbuf = cb * 4096;
        s16x8 af[4], bfr[4];
        #pragma unroll
        for (int i = 0; i < 4; i++) {
            af[i]  = *(const s16x8*)&AsF[cbuf + (wr*64 + i*16 + r)*32 + sw];
            bfr[i] = *(const s16x8*)&BsF[cbuf + (wc*64 + i*16 + r)*32 + sw];
        }
        #pragma unroll
        for (int i = 0; i < 4; i++)
            #pragma unroll
            for (int j = 0; j < 4; j++)
                acc[i][j] = __builtin_amdgcn_mfma_f32_16x16x32_bf16(af[i], bfr[j], acc[i][j], 0, 0, 0);
        cb = (cb < 2) ? cb + 1 : 0;
    }

    const int sel = n0 / C_;
    const int off = n0 % C_;
    const float scl = (sel == 0) ? 0.125f : 1.0f;
    #pragma unroll
    for (int i = 0; i < 4; i++) {
        #pragma unroll
        for (int rr = 0; rr < 4; rr++) {
            int gm = m0 + wr*64 + i*16 + q4*4 + rr;
            if (gm < M_TOT) {
                int bb = gm / N_, n = gm - bb * N_;
                #pragma unroll
                for (int j = 0; j < 4; j++) {
                    int col = off + wc*64 + j*16 + r;
                    int h = col >> 6, d = col & 63;
                    float val = acc[i][j][rr] * scl;
                    unsigned short hi = f2bf(val);
                    unsigned short lo = f2bf(val - bf2f(hi));
                    size_t bh = (size_t)(bb*H_ + h);
                    if (sel <= 1) {
                        unsigned short* dst = (sel == 0 ? qe : ke) + (bh*NPAD + n)*128;
                        dst[d]      = hi;
                        dst[64 + d] = lo;
                    } else {
                        unsigned short* dst = vtp + bh*128*NPAD;
                        dst[(size_t)d*NPAD + n]        = hi;
                        dst[(size_t)(64 + d)*NPAD + n] = lo;
                    }
                }
            }
        }
    }
}

// ---------------------------------------------------------------------------
// L3: attn (r18 + setprio, 4 blocks/CU) + cls_logits
// ---------------------------------------------------------------------------
__global__ __launch_bounds__(256, 4) void fused_attn_logits_kernel(
    const unsigned short* __restrict__ qe, const unsigned short* __restrict__ ke,
    const unsigned short* __restrict__ vtp, unsigned short* __restrict__ ctxs,
    const float* __restrict__ x, double* __restrict__ dws)
{
    __shared__ unsigned short KP[64*128];     // 16 KB: K tile, then P (overlay)
    __shared__ unsigned short VP[128*64];     // 16 KB, swizzled

    if (blockIdx.x >= 816) {
        // ---- cls_logits body (LDS aliased onto KP) ----
        double* xsd = (double*)KP;            // 768 doubles = 6 KB
        const int lid = blockIdx.x - 816;
        const int j = lid % 1025, b = lid / 1025;
        const int t = threadIdx.x;
        const int w = t >> 6, lane = t & 63;
        const float* xr = x + ((size_t)b * N_ + j) * C_;
        for (int c = t; c < C_; c += 256) xsd[c] = (double)xr[c];
        __syncthreads();
        for (int hh = 0; hh < 3; hh++) {
            int h = w + hh * 4;
            const double* ms = dws + DMS + ((size_t)(b*H_ + h))*768;
            double s = 0.0;
            #pragma unroll
            for (int i = 0; i < 12; i++) {
                int c = lane + i*64;
                s += xsd[c] * ms[c];
            }
            #pragma unroll
            for (int o = 1; o < 64; o <<= 1) s += __shfl_xor(s, o);
            if (lane == 0) dws[DLG + ((size_t)(b*H_ + h))*1025 + j] = s;
        }
        return;
    }

    const int qt = blockIdx.x / 48;
    const int g  = blockIdx.x - qt * 48;
    const int h = g % 12, b = g / 12;
    const int t = threadIdx.x;
    const int w = t >> 6, lane = t & 63;
    const int quad = lane >> 4, r16 = lane & 15;
    const size_t bh = (size_t)(b*H_ + h);

    // Q fragments (kt-invariant)
    s16x8 ah0, ah1, al0, al1;
    {
        const unsigned short* qrow = qe + (bh*NPAD + qt*64 + w*16 + r16) * 128;
        const int q8 = quad * 8;
        ah0 = *(const s16x8*)(qrow + q8);
        ah1 = *(const s16x8*)(qrow + 32 + q8);
        al0 = *(const s16x8*)(qrow + 64 + q8);
        al1 = *(const s16x8*)(qrow + 96 + q8);
    }

    int qu;
    {
        int rlo = qt*64, rhi = min(qt*64 + 63, N_ - 1);
        if (rlo == 0) qu = -2;
        else { int b1 = (rlo-1)>>8, b2 = (rhi-1)>>8; qu = (b1==b2) ? b1 : -2; }
    }

    float m_run[4], l_run[4];
    f32x4 ctx[4];
    #pragma unroll
    for (int i = 0; i < 4; i++) {
        m_run[i] = -1e30f; l_run[i] = 0.f;
        #pragma unroll
        for (int e = 0; e < 4; e++) ctx[i][e] = 0.f;
    }

    const unsigned short* keb = ke  + (bh*NPAD) * 128;
    const unsigned short* vtb = vtp + bh*(size_t)128*NPAD;

    const int kchunk = (t & 15) ^ ((t >> 4) & 15);
    const int vchunk = (t & 7)  ^ ((t >> 3) & 7);
    const unsigned short* kg0 = keb + (size_t)(t >> 4) * 128 + kchunk * 8;
    const unsigned short* vg0 = vtb + (size_t)(t >> 3) * NPAD + vchunk * 8;

    const int s0 = (quad ^ r16) << 3;
    const int sv = (quad ^ (r16 & 7)) << 3;
    unsigned short* Pew = KP + w*16*128;

    for (int kt = 0; kt < 17; kt++) {
        if (qu >= 0 && kt > 0) {
            int clo = kt*64, chi = min(kt*64 + 63, N_ - 1);
            int b1 = (clo-1)>>8, b2 = (chi-1)>>8;
            if (b1 == b2 && b1 == qu) continue;
        }

        __syncthreads();   // barrier1
        {
            const unsigned short* kg = kg0 + (size_t)kt * 64 * 128;
            const unsigned short* vg = vg0 + kt * 64;
            #pragma unroll
            for (int i = 0; i < 4; i++) {
                gl2lds16(kg + i * 2048,              KP + i*2048 + w*512);
                gl2lds16(vg + (size_t)i * 32 * NPAD, VP + i*2048 + w*512);
            }
        }
        __syncthreads();   // barrier2

        // ---- QK^T ----
        f32x4 st[4];
        #pragma unroll
        for (int j = 0; j < 4; j++)
            #pragma unroll
            for (int e = 0; e < 4; e++) st[j][e] = 0.f;
        __builtin_amdgcn_s_setprio(1);
        #pragma unroll
        for (int j = 0; j < 4; j++) {
            const unsigned short* kr = &KP[(j*16 + r16) * 128];
            s16x8 bh0 = *(const s16x8*)&kr[s0];
            s16x8 bh1 = *(const s16x8*)&kr[s0 ^ 32];
            s16x8 bl0 = *(const s16x8*)&kr[s0 ^ 64];
            s16x8 bl1 = *(const s16x8*)&kr[s0 ^ 96];
            st[j] = __builtin_amdgcn_mfma_f32_16x16x32_bf16(ah0, bh0, st[j], 0,0,0);
            st[j] = __builtin_amdgcn_mfma_f32_16x16x32_bf16(ah1, bh1, st[j], 0,0,0);
            st[j] = __builtin_amdgcn_mfma_f32_16x16x32_bf16(ah0, bl0, st[j], 0,0,0);
            st[j] = __builtin_amdgcn_mfma_f32_16x16x32_bf16(ah1, bl1, st[j], 0,0,0);
            st[j] = __builtin_amdgcn_mfma_f32_16x16x32_bf16(al0, bh0, st[j], 0,0,0);
            st[j] = __builtin_amdgcn_mfma_f32_16x16x32_bf16(al1, bh1, st[j], 0,0,0);
        }
        __builtin_amdgcn_s_setprio(0);

        // ---- online softmax ----
        float pv[4][4];
        float alpha[4];
        #pragma unroll
        for (int reg = 0; reg < 4; reg++) {
            int gr = qt*64 + w*16 + quad*4 + reg;
            int qb = (gr >= 1) ? ((gr - 1) >> 8) : -1;
            float mx = -1e30f;
            float vv[4];
            #pragma unroll
            for (int j = 0; j < 4; j++) {
                int gc = kt*64 + j*16 + r16;
                bool ok = (gr < N_) && (gc < N_) &&
                          !((gr >= 1) && (gc >= 1) && (((gc - 1) >> 8) == qb));
                vv[j] = ok ? st[j][reg] : -1e30f;
                mx = fmaxf(mx, vv[j]);
            }
            mx = fmaxf(mx, __shfl_xor(mx, 1));
            mx = fmaxf(mx, __shfl_xor(mx, 2));
            mx = fmaxf(mx, __shfl_xor(mx, 4));
            mx = fmaxf(mx, __shfl_xor(mx, 8));
            float mnew = fmaxf(m_run[reg], mx);
            alpha[reg] = __expf(m_run[reg] - mnew);
            m_run[reg] = mnew;
            float ps = 0.f;
            #pragma unroll
            for (int j = 0; j < 4; j++) {
                float pp = (vv[j] > -1e29f) ? __expf(vv[j] - mnew) : 0.f;
                pv[reg][j] = pp; ps += pp;
            }
            ps += __shfl_xor(ps, 1);
            ps += __shfl_xor(ps, 2);
            ps += __shfl_xor(ps, 4);
            ps += __shfl_xor(ps, 8);
            l_run[reg] = l_run[reg] * alpha[reg] + ps;
        }

        __syncthreads();   // barrier3: K dead -> P overlay OK

        #pragma unroll
        for (int reg = 0; reg < 4; reg++) {
            int lrow = quad*4 + reg;
            #pragma unroll
            for (int j = 0; j < 4; j++) {
                float pp = pv[reg][j];
                unsigned short ph = f2bf(pp);
                unsigned short pl = f2bf(pp - bf2f(ph));
                int colh = j*16 + r16;
                int coll = 64 + colh;
                Pew[lrow*128 + (((colh >> 3) ^ lrow) << 3) + (colh & 7)] = ph;
                Pew[lrow*128 + (((coll >> 3) ^ lrow) << 3) + (coll & 7)] = pl;
            }
        }

        #pragma unroll
        for (int nj = 0; nj < 4; nj++)
            #pragma unroll
            for (int reg = 0; reg < 4; reg++)
                ctx[nj][reg] *= alpha[reg];

        // ---- PV ----
        {
            const unsigned short* pr = &Pew[r16 * 128];
            s16x8 ph0 = *(const s16x8*)&pr[s0];
            s16x8 ph1 = *(const s16x8*)&pr[s0 ^ 32];
            s16x8 pl0 = *(const s16x8*)&pr[s0 ^ 64];
            s16x8 pl1 = *(const s16x8*)&pr[s0 ^ 96];
            __builtin_amdgcn_s_setprio(1);
            #pragma unroll
            for (int nj = 0; nj < 4; nj++) {
                const unsigned short* vh = &VP[(nj*16 + r16) * 64];
                const unsigned short* vl = &VP[(64 + nj*16 + r16) * 64];
                s16x8 vh0 = *(const s16x8*)&vh[sv];
                s16x8 vh1 = *(const s16x8*)&vh[sv ^ 32];
                s16x8 vl0 = *(const s16x8*)&vl[sv];
                s16x8 vl1 = *(const s16x8*)&vl[sv ^ 32];
                ctx[nj] = __builtin_amdgcn_mfma_f32_16x16x32_bf16(ph0, vh0, ctx[nj], 0,0,0);
                ctx[nj] = __builtin_amdgcn_mfma_f32_16x16x32_bf16(ph1, vh1, ctx[nj], 0,0,0);
                ctx[nj] = __builtin_amdgcn_mfma_f32_16x16x32_bf16(ph0, vl0, ctx[nj], 0,0,0);
                ctx[nj] = __builtin_amdgcn_mfma_f32_16x16x32_bf16(ph1, vl1, ctx[nj], 0,0,0);
                ctx[nj] = __builtin_amdgcn_mfma_f32_16x16x32_bf16(pl0, vh0, ctx[nj], 0,0,0);
                ctx[nj] = __builtin_amdgcn_mfma_f32_16x16x32_bf16(pl1, vh1, ctx[nj], 0,0,0);
            }
            __builtin_amdgcn_s_setprio(0);
        }
    }

    #pragma unroll
    for (int reg = 0; reg < 4; reg++) {
        int gr = qt*64 + w*16 + quad*4 + reg;
        if (gr < N_) {
            float inv = 1.0f / l_run[reg];
            size_t row = (size_t)(b*N_ + gr) * KEXP;
            #pragma unroll
            for (int nj = 0; nj < 4; nj++) {
                float val = ctx[nj][reg] * inv;
                unsigned short hi = f2bf(val);
                unsigned short lo = f2bf(val - bf2f(hi));
                int c = h*64 + nj*16 + r16;
                ctxs[row + c]        = hi;
                ctxs[row + 768 + c]  = hi;
                ctxs[row + 1536 + c] = lo;
            }
        }
    }
}

// ---------------------------------------------------------------------------
// L4: gemm_out 64x128 (+ T1 XCD) + cls_reduce
// ---------------------------------------------------------------------------
__global__ __launch_bounds__(256, 4) void fused_gemm_out_reduce_kernel(
    const unsigned short* __restrict__ A, const unsigned short* __restrict__ Bm,
    const float* __restrict__ bias, float* __restrict__ out,
    double* __restrict__ dws)
{
    __shared__ unsigned short AsF[3*2048];
    __shared__ unsigned short BsF[3*4096];

    if (blockIdx.x >= OUT_BLOCKS) {
        // ---- cls_reduce body (LDS aliased onto AsF) ----
        double* red = (double*)AsF;           // 256 doubles = 2 KB
        const int lid = blockIdx.x - OUT_BLOCKS;
        const int h = lid % 12, b = lid / 12;
        const int t = threadIdx.x;
        const double* lg = dws + DLG + ((size_t)(b*H_ + h))*1025;
        double mloc = -1e300;
        for (int j = t; j < N_; j += 256) mloc = fmax(mloc, lg[j]);
        red[t] = mloc; __syncthreads();
        for (int o = 128; o > 0; o >>= 1) {
            if (t < o) red[t] = fmax(red[t], red[t+o]);
            __syncthreads();
        }
        double mx = red[0]; __syncthreads();
        double sloc = 0.0;
        for (int j = t; j < N_; j += 256) sloc += exp(lg[j] - mx);
        red[t] = sloc; __syncthreads();
        for (int o = 128; o > 0; o >>= 1) {
            if (t < o) red[t] += red[t+o];
            __syncthreads();
        }
        if (t == 0) {
            dws[DMX + b*H_ + h] = mx;
            dws[DZ  + b*H_ + h] = red[0];
        }
        return;
    }

    int mi, ni;
    gemm_decode2(xcd_chunk(blockIdx.x, OUT_BLOCKS), OUT_MT, OUT_NT, mi, ni);
    const int n0 = ni * 128;
    const int m0 = mi * 64;
    const int t = threadIdx.x;
    const int lane = t & 63, wv = t >> 6;
    const int q4 = lane >> 4, r = lane & 15;
    const int lrr = lane >> 2;
    const int lcc = ((lane & 3) ^ ((lane >> 3) & 3)) * 8;
    const int sw  = (q4 ^ ((r >> 1) & 3)) * 8;

    f32x4 acc[4][2];
    #pragma unroll
    for (int i = 0; i < 4; i++)
        #pragma unroll
        for (int j = 0; j < 2; j++)
            #pragma unroll
            for (int e = 0; e < 4; e++) acc[i][j][e] = 0.f;

    const unsigned short* gA = A  + (size_t)(m0 + wv*16 + lrr) * KEXP + lcc;
    const unsigned short* gB = Bm + (size_t)(n0 + wv*16 + lrr) * KEXP + lcc;

    auto STAGE = [&](int kt, int buf) {
        const unsigned short* a = gA + kt * 32;
        const unsigned short* b = gB + kt * 32;
        gl2lds16(a,                       AsF + buf*2048 + wv*512);
        gl2lds16(b,                       BsF + buf*4096 + wv*512);
        gl2lds16(b + (size_t)64 * KEXP,   BsF + buf*4096 + 2048 + wv*512);
    };

    STAGE(0, 0);
    STAGE(1, 1);

    int cb = 0;
    for (int it = 0; it < 72; ++it) {
        if (it + 1 < 72) asm volatile("s_waitcnt vmcnt(3)" ::: "memory");
        else             asm volatile("s_waitcnt vmcnt(0)" ::: "memory");
        __builtin_amdgcn_s_barrier();
        asm volatile("" ::: "memory");
        __builtin_amdgcn_sched_barrier(0);
        if (it + 2 < 72) {
            int nb = (cb >= 1) ? cb - 1 : cb + 2;
            STAGE(it + 2, nb);
        }
        const int cA = cb * 2048, cB = cb * 4096;
        s16x8 af[4], bfr[2];
        #pragma unroll
        for (int i = 0; i < 4; i++)
            af[i]  = *(const s16x8*)&AsF[cA + (i*16 + r)*32 + sw];
        #pragma unroll
        for (int j = 0; j < 2; j++)
            bfr[j] = *(const s16x8*)&BsF[cB + (wv*32 + j*16 + r)*32 + sw];
        #pragma unroll
        for (int i = 0; i < 4; i++)
            #pragma unroll
            for (int j = 0; j < 2; j++)
                acc[i][j] = __builtin_amdgcn_mfma_f32_16x16x32_bf16(af[i], bfr[j], acc[i][j], 0, 0, 0);
        cb = (cb < 2) ? cb + 1 : 0;
    }

    #pragma unroll
    for (int i = 0; i < 4; i++) {
        #pragma unroll
        for (int rr = 0; rr < 4; rr++) {
            int gm = m0 + i*16 + q4*4 + rr;
            if (gm < M_TOT) {
                #pragma unroll
                for (int j = 0; j < 2; j++) {
                    int col = n0 + wv*32 + j*16 + r;
                    out[(size_t)gm * C_ + col] = acc[i][j][rr] + bias[col];
                }
            }
        }
    }
}

// ---------------------------------------------------------------------------
// cls tail: score, rank, fill (r21/r25 measured-good 3-kernel version)
// ---------------------------------------------------------------------------
__global__ __launch_bounds__(256) void cls_score_kernel(
    const double* __restrict__ dwsr, double* __restrict__ dws,
    float* __restrict__ out)
{
    const int idx = blockIdx.x * 256 + threadIdx.x;   // 0..4095
    const int b = idx >> 10, t = idx & 1023;
    double s = 0.0;
    #pragma unroll
    for (int h = 0; h < H_; h++) {
        double mx = dwsr[DMX + b*H_ + h];
        double Z  = dwsr[DZ  + b*H_ + h];
        double lg = dwsr[DLG + ((size_t)(b*H_ + h))*1025 + (t + 1)];
        s += exp(lg - mx) / Z;
    }
    s *= (1.0 / 12.0);
    dws[DMV + idx] = s;
    out[OFF_CLS + (size_t)b*1024 + t] = (float)s;
}

__global__ __launch_bounds__(256) void cls_rank_kernel(
    const double* __restrict__ dws, float* __restrict__ out)
{
    __shared__ double mv[1024];
    const int q = blockIdx.x, b = blockIdx.y;
    const int tid = threadIdx.x;
    for (int i = tid; i < 1024; i += 256) mv[i] = dws[DMV + b*1024 + i];
    __syncthreads();
    const int t = q*256 + tid;
    const double v = mv[t];
    int cd = 0, ca = 0;
    #pragma unroll 8
    for (int j = 0; j < 1024; j++) {
        double u = mv[j];
        bool tie = (u == v) && (j < t);
        cd += (u > v) || tie;
        ca += (u < v) || tie;
    }
    if (cd < 103) out[OFF_EIDX + (size_t)b*103 + cd] = (float)t;
    if (ca < 103) out[OFF_FIDX + (size_t)b*103 + ca] = (float)t;
}

__global__ __launch_bounds__(256) void cls_fill_kernel(float* __restrict__ out)
{
    const int PER = 103 * 192;                   // float4 per (array,b)
    int idx = blockIdx.x * 256 + threadIdx.x;
    if (idx >= 2 * 4 * PER) return;
    int sel = idx / (4 * PER);                   // 0 = enhance, 1 = fuse
    int r   = idx - sel * 4 * PER;
    int b   = r / PER;
    int rem = r - b * PER;
    int e   = rem / 192;
    int c4  = (rem - e * 192) * 4;
    float val = out[(sel ? OFF_FIDX : OFF_EIDX) + (size_t)b*103 + e];
    float* dst = out + (sel ? OFF_FIND : OFF_EIND) + ((size_t)b*103 + e)*768 + c4;
    *(float4*)dst = make_float4(val, val, val, val);
}

// ---------------------------------------------------------------------------
extern "C" void kernel_launch(void* const* d_in, const int* in_sizes, int n_in,
                              void* d_out, int out_size, void* d_ws, size_t ws_size,
                              hipStream_t stream)
{
    const float* x     = (const float*)d_in[0];
    const float* w_qkv = (const float*)d_in[1];
    const float* w_out = (const float*)d_in[2];
    const float* b_out = (const float*)d_in[3];
    float* out = (float*)d_out;
    float* ws  = (float*)d_ws;

    double* dws = (double*)(ws + WS_F64);
    unsigned short* xs   = (unsigned short*)(ws + WS_XS);   // x'; later ctx'
    unsigned short* qkvB = (unsigned short*)(ws + WS_QKVB);
    unsigned short* outB = (unsigned short*)(ws + WS_OUTB);
    unsigned short* qe   = (unsigned short*)(ws + WS_QE);
    unsigned short* ke   = (unsigned short*)(ws + WS_KE);
    unsigned short* vtp  = (unsigned short*)(ws + WS_VT);

    fused_split_q0_kernel<<<SPLIT_BLOCKS + 768, 256, 0, stream>>>(
        x, w_qkv, w_out, xs, qkvB, outB, dws);

    fused_gemm_qkv_ms_kernel<<<QKV_BLOCKS + 144, 256, 0, stream>>>(
        xs, qkvB, qe, ke, vtp, w_qkv, dws);

    fused_attn_logits_kernel<<<816 + 4100, 256, 0, stream>>>(
        qe, ke, vtp, xs, x, dws);

    fused_gemm_out_reduce_kernel<<<OUT_BLOCKS + 48, 256, 0, stream>>>(
        xs, outB, b_out, out, dws);

    cls_score_kernel<<<16, 256, 0, stream>>>(dws, dws, out);
    cls_rank_kernel<<<dim3(4, B_), 256, 0, stream>>>(dws, out);
    cls_fill_kernel<<<618, 256, 0, stream>>>(out);
}